// Round 1
// baseline (232.594 us; speedup 1.0000x reference)
//
#include <hip/hip_runtime.h>
#include <math.h>

#define BATCH 8
#define TLEN  512
#define DDIM  512
#define TOUT  608   // 512 + 96
#define KSEL  32

// ws layout (floats):
//   re : [8][256][512]   offset 0
//   im : [8][256][512]   offset 1048576
//   tm : [8][32][512]    offset 2097152 (int)
//   tre: [8][32][512]    offset 2228224
//   tim: [8][32][512]    offset 2359296
#define RE_OFF  0
#define IM_OFF  1048576
#define TM_OFF  2097152
#define TRE_OFF 2228224
#define TIM_OFF 2359296

#define TWO_PI_OVER_512 0.0122718463030851562f

// ---------------------------------------------------------------------------
// Kernel 1: direct DFT.  X[b,m,d] = sum_t x[b,t,d] * exp(-2*pi*i*m*t/512)
// Block: 256 threads computes a 64m x 64d tile for one batch.
// Grid: 8 b * 4 m-tiles * 8 d-tiles = 256 blocks.
// ---------------------------------------------------------------------------
__global__ __launch_bounds__(256) void dft_kernel(const float* __restrict__ x,
                                                  float* __restrict__ ws) {
    __shared__ float tab[512];
    __shared__ __align__(16) float xs[64][68];   // 64 t rows, pad 68 (16B-aligned rows)

    const int tid = threadIdx.x;
    for (int k = tid; k < 512; k += 256)
        tab[k] = cosf((float)k * TWO_PI_OVER_512);

    const int blk    = blockIdx.x;
    const int b      = blk >> 5;
    const int m_base = ((blk >> 3) & 3) * 64;
    const int d_base = (blk & 7) * 64;

    const int lane_d = tid & 15;   // 16 d-quads
    const int lane_m = tid >> 4;   // 16 m-quads
    const int m0 = m_base + lane_m * 4;
    const int d0 = d_base + lane_d * 4;

    float racc[4][4] = {};
    float iacc[4][4] = {};
    int   idx[4]     = {0, 0, 0, 0};

    const float* xb = x + (size_t)b * TLEN * DDIM;

    const int tl0 = tid >> 6;    // 0..3
    const int dl  = tid & 63;

    for (int chunk = 0; chunk < 8; ++chunk) {
        __syncthreads();   // also covers initial table fill
        #pragma unroll
        for (int i = 0; i < 16; ++i) {
            int tl = tl0 + i * 4;
            xs[tl][dl] = xb[(size_t)(chunk * 64 + tl) * DDIM + d_base + dl];
        }
        __syncthreads();

        for (int t = 0; t < 64; ++t) {
            float4 xv = *reinterpret_cast<const float4*>(&xs[t][lane_d * 4]);
            float xr[4] = {xv.x, xv.y, xv.z, xv.w};
            #pragma unroll
            for (int i = 0; i < 4; ++i) {
                float c = tab[idx[i]];
                float s = tab[(idx[i] + 384) & 511];
                #pragma unroll
                for (int j = 0; j < 4; ++j) {
                    racc[i][j] = fmaf(c, xr[j], racc[i][j]);
                    iacc[i][j] = fmaf(-s, xr[j], iacc[i][j]);
                }
                idx[i] = (idx[i] + m0 + i) & 511;
            }
        }
    }

    float* re = ws + RE_OFF;
    float* im = ws + IM_OFF;
    #pragma unroll
    for (int i = 0; i < 4; ++i) {
        int m = m0 + i;
        #pragma unroll
        for (int j = 0; j < 4; ++j) {
            size_t o = ((size_t)b * 256 + m) * DDIM + d0 + j;
            re[o] = racc[i][j];
            im[o] = iacc[i][j];
        }
    }
}

// ---------------------------------------------------------------------------
// Kernel 2: per-(b,d) top-32 of |X_m|^2 over m=1..255.
// One wave (64 threads) per column; 4096 blocks.
// ---------------------------------------------------------------------------
__global__ __launch_bounds__(64) void topk_kernel(float* __restrict__ ws) {
    const int bd = blockIdx.x;
    const int b  = bd >> 9;
    const int d  = bd & 511;
    const int l  = threadIdx.x;

    const float* re = ws + RE_OFF;
    const float* im = ws + IM_OFF;
    int*   tm  = (int*)(ws + TM_OFF);
    float* tre = ws + TRE_OFF;
    float* tim = ws + TIM_OFF;

    float v[4];
    int   mv[4];
    #pragma unroll
    for (int s = 0; s < 4; ++s) {
        int m = 1 + l + 64 * s;
        if (m <= 255) {
            size_t o = ((size_t)b * 256 + m) * DDIM + d;
            float r = re[o], q = im[o];
            v[s]  = fmaf(r, r, q * q);
            mv[s] = m;
        } else {
            v[s]  = -1.0f;
            mv[s] = 0;
        }
    }

    for (int j = 0; j < KSEL; ++j) {
        float bv = v[0]; int bs = 0;
        #pragma unroll
        for (int s = 1; s < 4; ++s)
            if (v[s] > bv) { bv = v[s]; bs = s; }
        int bm = mv[bs];

        float rv = bv; int rm = bm;
        #pragma unroll
        for (int off = 1; off < 64; off <<= 1) {
            float ov = __shfl_xor(rv, off);
            int   om = __shfl_xor(rm, off);
            if (ov > rv) { rv = ov; rm = om; }
        }

        unsigned long long mask = __ballot(bv == rv);
        int owner = __ffsll(mask) - 1;
        if (l == owner) v[bs] = -1.0f;

        if (l == 0) {
            size_t src = ((size_t)b * 256 + rm) * DDIM + d;
            size_t dst = ((size_t)b * KSEL + j) * DDIM + d;
            tm[dst]  = rm;
            tre[dst] = re[src];
            tim[dst] = im[src];
        }
    }
}

// ---------------------------------------------------------------------------
// Kernel 3: synthesis.  out[b,tt,d] = sum_j (2/512)*(Re_j*cos - Im_j*sin),
// angle index = (m_j * tt) & 511.
// Block: 256 threads = 256 consecutive d; 16 tt per block.
// Grid: 8 b * 2 d-halves * 38 t-tiles = 608 blocks.
// ---------------------------------------------------------------------------
__global__ __launch_bounds__(256) void synth_kernel(const float* __restrict__ ws,
                                                    float* __restrict__ out) {
    __shared__ float tab[512];
    const int tid = threadIdx.x;
    for (int k = tid; k < 512; k += 256)
        tab[k] = cosf((float)k * TWO_PI_OVER_512);
    __syncthreads();

    const int blk = blockIdx.x;
    const int b   = blk / 76;
    const int r   = blk % 76;
    const int dh  = r / 38;
    const int tt  = r % 38;
    const int d   = dh * 256 + tid;
    const int t0  = tt * 16;

    const int*   tm  = (const int*)(ws + TM_OFF);
    const float* tre = ws + TRE_OFF;
    const float* tim = ws + TIM_OFF;

    float acc[16] = {};

    for (int j = 0; j < KSEL; ++j) {
        size_t o = ((size_t)b * KSEL + j) * DDIM + d;
        int   m = tm[o];
        float a = tre[o] * (2.0f / 512.0f);
        float g = tim[o] * (2.0f / 512.0f);
        int idx = (m * t0) & 511;
        #pragma unroll
        for (int t = 0; t < 16; ++t) {
            float c = tab[idx];
            float s = tab[(idx + 384) & 511];
            acc[t] = fmaf(a, c, acc[t]);
            acc[t] = fmaf(-g, s, acc[t]);
            idx = (idx + m) & 511;
        }
    }

    float* ob = out + (size_t)b * TOUT * DDIM;
    #pragma unroll
    for (int t = 0; t < 16; ++t)
        ob[(size_t)(t0 + t) * DDIM + d] = acc[t];
}

extern "C" void kernel_launch(void* const* d_in, const int* in_sizes, int n_in,
                              void* d_out, int out_size, void* d_ws, size_t ws_size,
                              hipStream_t stream) {
    const float* x   = (const float*)d_in[0];
    float*       out = (float*)d_out;
    float*       ws  = (float*)d_ws;

    dft_kernel<<<256, 256, 0, stream>>>(x, ws);
    topk_kernel<<<BATCH * DDIM, 64, 0, stream>>>(ws);
    synth_kernel<<<BATCH * 2 * 38, 256, 0, stream>>>(ws, out);
}

// Round 2
// 132.503 us; speedup vs baseline: 1.7554x; 1.7554x over previous
//
#include <hip/hip_runtime.h>
#include <math.h>

#define BATCH 8
#define TLEN  512
#define DDIM  512
#define TOUT  608   // 512 + 96
#define KSEL  32
#define NFREQ 256   // we compute m = 0..255; only 1..255 used by top-k

#define TWO_PI_OVER_512 0.0122718463030851562f

// ---------------------------------------------------------------------------
// Kernel 1: direct DFT, t-split into ts_count partials for occupancy.
// Block: 256 threads computes a 64m x 64d tile over (512/ts_count) t values.
// Grid: 256 * ts_count.  Partial output layout: [ts][b][d][m] (m innermost!)
// ---------------------------------------------------------------------------
__global__ __launch_bounds__(256) void dft_kernel(const float* __restrict__ x,
                                                  float* __restrict__ pre,
                                                  float* __restrict__ pim,
                                                  int ts_count) {
    __shared__ float tab[512];
    __shared__ __align__(16) float xs[64][68];   // 64 t rows, pad to 68

    const int tid = threadIdx.x;
    for (int k = tid; k < 512; k += 256)
        tab[k] = cosf((float)k * TWO_PI_OVER_512);

    const int blk    = blockIdx.x;
    const int ts     = blk >> 8;          // which t-partial
    const int rem    = blk & 255;
    const int b      = rem >> 5;
    const int m_base = ((rem >> 3) & 3) * 64;
    const int d_base = (rem & 7) * 64;

    const int lane_d = tid & 15;
    const int lane_m = tid >> 4;
    const int m0 = m_base + lane_m * 4;
    const int d0 = d_base + lane_d * 4;

    const int cpp     = 8 / ts_count;     // 64-t chunks per partial
    const int c0      = ts * cpp;
    const int t_start = c0 * 64;

    float racc[4][4] = {};
    float iacc[4][4] = {};
    int   idx[4];
    #pragma unroll
    for (int i = 0; i < 4; ++i)
        idx[i] = ((m0 + i) * t_start) & 511;

    const float* xb = x + (size_t)b * TLEN * DDIM;
    const int tl0 = tid >> 6;    // 0..3
    const int dl  = tid & 63;

    for (int chunk = c0; chunk < c0 + cpp; ++chunk) {
        __syncthreads();
        #pragma unroll
        for (int i = 0; i < 16; ++i) {
            int tl = tl0 + i * 4;
            xs[tl][dl] = xb[(size_t)(chunk * 64 + tl) * DDIM + d_base + dl];
        }
        __syncthreads();

        #pragma unroll 4
        for (int t = 0; t < 64; ++t) {
            float4 xv = *reinterpret_cast<const float4*>(&xs[t][lane_d * 4]);
            float xr[4] = {xv.x, xv.y, xv.z, xv.w};
            #pragma unroll
            for (int i = 0; i < 4; ++i) {
                float c = tab[idx[i]];
                float s = tab[(idx[i] + 384) & 511];
                #pragma unroll
                for (int j = 0; j < 4; ++j) {
                    racc[i][j] = fmaf(c, xr[j], racc[i][j]);
                    iacc[i][j] = fmaf(-s, xr[j], iacc[i][j]);
                }
                idx[i] = (idx[i] + m0 + i) & 511;
            }
        }
    }

    // transposed store: [ts][b][d][m], 4 consecutive m per float4
    float* reb = pre + (size_t)(ts * BATCH + b) * DDIM * NFREQ;
    float* imb = pim + (size_t)(ts * BATCH + b) * DDIM * NFREQ;
    #pragma unroll
    for (int j = 0; j < 4; ++j) {
        float4 rv = make_float4(racc[0][j], racc[1][j], racc[2][j], racc[3][j]);
        float4 iv = make_float4(iacc[0][j], iacc[1][j], iacc[2][j], iacc[3][j]);
        size_t o = (size_t)(d0 + j) * NFREQ + m0;
        *reinterpret_cast<float4*>(reb + o) = rv;
        *reinterpret_cast<float4*>(imb + o) = iv;
    }
}

// ---------------------------------------------------------------------------
// Kernel 2: per-(b,d) sum the t-partials and take top-32 of |X_m|^2, m=1..255.
// One wave per column; reads are m-contiguous (coalesced) in the new layout.
// ---------------------------------------------------------------------------
__global__ __launch_bounds__(64) void topk_kernel(const float* __restrict__ pre,
                                                  const float* __restrict__ pim,
                                                  int*   __restrict__ tm,
                                                  float* __restrict__ tre,
                                                  float* __restrict__ tim,
                                                  int ts_count) {
    const int bd = blockIdx.x;
    const int b  = bd >> 9;
    const int d  = bd & 511;
    const int l  = threadIdx.x;

    float v[4], rs[4], qs[4];
    int   mv[4];
    #pragma unroll
    for (int s = 0; s < 4; ++s) {
        int m = 1 + l + 64 * s;
        float r = 0.f, q = 0.f;
        if (m <= 255) {
            for (int ts = 0; ts < ts_count; ++ts) {
                size_t o = ((size_t)(ts * BATCH + b) * DDIM + d) * NFREQ + m;
                r += pre[o];
                q += pim[o];
            }
            v[s]  = fmaf(r, r, q * q);
            mv[s] = m;
        } else {
            v[s]  = -1.0f;
            mv[s] = 0;
        }
        rs[s] = r;
        qs[s] = q;
    }

    for (int j = 0; j < KSEL; ++j) {
        float bv = v[0], br = rs[0], bq = qs[0];
        int   bm = mv[0], bs = 0;
        #pragma unroll
        for (int s = 1; s < 4; ++s)
            if (v[s] > bv) { bv = v[s]; br = rs[s]; bq = qs[s]; bm = mv[s]; bs = s; }

        float rv = bv;
        #pragma unroll
        for (int off = 1; off < 64; off <<= 1) {
            float ov = __shfl_xor(rv, off);
            rv = ov > rv ? ov : rv;
        }

        unsigned long long mask = __ballot(bv == rv);
        int owner = __ffsll(mask) - 1;
        bool own = (l == owner);
        if (own) {
            size_t dst = ((size_t)b * KSEL + j) * DDIM + d;
            tm[dst]  = bm;
            tre[dst] = br;
            tim[dst] = bq;
        }
        v[0] = (own && bs == 0) ? -1.0f : v[0];
        v[1] = (own && bs == 1) ? -1.0f : v[1];
        v[2] = (own && bs == 2) ? -1.0f : v[2];
        v[3] = (own && bs == 3) ? -1.0f : v[3];
    }
}

// ---------------------------------------------------------------------------
// Kernel 3: synthesis.  out[b,tt,d] = sum_j (2/512)*(Re_j*cos - Im_j*sin),
// angle index = (m_j * tt) & 511.
// ---------------------------------------------------------------------------
__global__ __launch_bounds__(256) void synth_kernel(const int*   __restrict__ tm,
                                                    const float* __restrict__ tre,
                                                    const float* __restrict__ tim,
                                                    float* __restrict__ out) {
    __shared__ float tab[512];
    const int tid = threadIdx.x;
    for (int k = tid; k < 512; k += 256)
        tab[k] = cosf((float)k * TWO_PI_OVER_512);
    __syncthreads();

    const int blk = blockIdx.x;
    const int b   = blk / 76;
    const int r   = blk % 76;
    const int dh  = r / 38;
    const int tt  = r % 38;
    const int d   = dh * 256 + tid;
    const int t0  = tt * 16;

    float acc[16] = {};

    for (int j = 0; j < KSEL; ++j) {
        size_t o = ((size_t)b * KSEL + j) * DDIM + d;
        int   m = tm[o];
        float a = tre[o] * (2.0f / 512.0f);
        float g = tim[o] * (2.0f / 512.0f);
        int idx = (m * t0) & 511;
        #pragma unroll
        for (int t = 0; t < 16; ++t) {
            float c = tab[idx];
            float s = tab[(idx + 384) & 511];
            acc[t] = fmaf(a, c, acc[t]);
            acc[t] = fmaf(-g, s, acc[t]);
            idx = (idx + m) & 511;
        }
    }

    float* ob = out + (size_t)b * TOUT * DDIM;
    #pragma unroll
    for (int t = 0; t < 16; ++t)
        ob[(size_t)(t0 + t) * DDIM + d] = acc[t];
}

extern "C" void kernel_launch(void* const* d_in, const int* in_sizes, int n_in,
                              void* d_out, int out_size, void* d_ws, size_t ws_size,
                              hipStream_t stream) {
    const float* x   = (const float*)d_in[0];
    float*       out = (float*)d_out;
    float*       ws  = (float*)d_ws;

    // pick largest t-split that fits ws
    int TS = 1;
    {
        const size_t topk_floats = (size_t)3 * BATCH * KSEL * DDIM;  // 393216
        for (int cand = 4; cand >= 1; cand >>= 1) {
            size_t part  = (size_t)cand * BATCH * DDIM * NFREQ;      // per array
            size_t bytes = (2 * part + topk_floats) * sizeof(float);
            if (bytes <= ws_size) { TS = cand; break; }
        }
    }

    size_t part = (size_t)TS * BATCH * DDIM * NFREQ;
    float* pre = ws;
    float* pim = ws + part;
    int*   tm  = (int*)(ws + 2 * part);
    float* tre = ws + 2 * part + (size_t)BATCH * KSEL * DDIM;
    float* tim = ws + 2 * part + (size_t)2 * BATCH * KSEL * DDIM;

    dft_kernel<<<256 * TS, 256, 0, stream>>>(x, pre, pim, TS);
    topk_kernel<<<BATCH * DDIM, 64, 0, stream>>>(pre, pim, tm, tre, tim, TS);
    synth_kernel<<<BATCH * 2 * 38, 256, 0, stream>>>(tm, tre, tim, out);
}

// Round 3
// 63.193 us; speedup vs baseline: 3.6807x; 2.0968x over previous
//
#include <hip/hip_runtime.h>
#include <math.h>

#define BATCH 8
#define TLEN  512
#define DDIM  512
#define TOUT  608   // 512 + 96
#define KSEL  32
#define NFREQ 256

#define TWO_PI_OVER_512 0.0122718463030851562f
#define TWO_PI_OVER_512_D (6.283185307179586476925287 / 512.0)

// ws layout (floats):
//   Zre: [8][16 q][32 a][512 d]   offset 0          (2,097,152)
//   Zim: same                      offset 2097152
//   Xre: [8][512 d][256 m]        offset 4194304    (1,048,576)
//   Xim: same                      offset 5242880
//   tm : [8][32][512] (int)       offset 6291456
//   tre: [8][32][512]             offset 6422528
//   tim: [8][32][512]             offset 6553600
#define ZRE_OFF 0
#define ZIM_OFF 2097152
#define XRE_OFF 4194304
#define XIM_OFF 5242880
#define TM_OFF  6291456
#define TRE_OFF 6422528
#define TIM_OFF 6553600

// ---------------------------------------------------------------------------
// Stage A: Y[b,a,q,d] = sum_{c<16} x[b, a+32c, d] * e^{-2pi i c q/16}
// Thread per (b,a,d). Grid 512 blocks x 256 threads.
// Twiddles are compile-time constants (fully unrolled 16x16).
// ---------------------------------------------------------------------------
__global__ __launch_bounds__(256) void fft_stage_a(const float* __restrict__ x,
                                                   float* __restrict__ zre,
                                                   float* __restrict__ zim) {
    const int blk = blockIdx.x;            // 8b * 32a * 2dh
    const int b   = blk >> 6;
    const int a   = (blk >> 1) & 31;
    const int d   = ((blk & 1) << 8) + threadIdx.x;

    const float* xb = x + ((size_t)b * TLEN + a) * DDIM + d;
    float xv[16];
    #pragma unroll
    for (int c = 0; c < 16; ++c)
        xv[c] = xb[(size_t)c * 32 * DDIM];

    const float CC[16] = { 1.f,  0.923879533f,  0.707106781f,  0.382683432f,
                           0.f, -0.382683432f, -0.707106781f, -0.923879533f,
                          -1.f, -0.923879533f, -0.707106781f, -0.382683432f,
                           0.f,  0.382683432f,  0.707106781f,  0.923879533f };
    const float SS[16] = { 0.f,  0.382683432f,  0.707106781f,  0.923879533f,
                           1.f,  0.923879533f,  0.707106781f,  0.382683432f,
                           0.f, -0.382683432f, -0.707106781f, -0.923879533f,
                          -1.f, -0.923879533f, -0.707106781f, -0.382683432f };

    #pragma unroll
    for (int q = 0; q < 16; ++q) {
        float yr = 0.f, yi = 0.f;
        #pragma unroll
        for (int c = 0; c < 16; ++c) {
            const int n = (c * q) & 15;
            yr = fmaf(xv[c],  CC[n], yr);
            yi = fmaf(xv[c], -SS[n], yi);
        }
        size_t o = (((size_t)b * 16 + q) * 32 + a) * DDIM + d;
        zre[o] = yr;
        zim[o] = yi;
    }
}

// ---------------------------------------------------------------------------
// Stage B: X[b,d,k] = sum_{a<32} Y[b,a,k&15,d] * e^{-2pi i a k/512}
// Block = (b, q, d-tile 64), 1024 threads: tid&63 = d, tid>>6 = j, k = q+16j.
// k is wave-uniform -> twiddle table reads are broadcast. Exact table values.
// ---------------------------------------------------------------------------
__global__ __launch_bounds__(1024) void fft_stage_b(const float* __restrict__ zre,
                                                    const float* __restrict__ zim,
                                                    float* __restrict__ xre,
                                                    float* __restrict__ xim) {
    __shared__ float2 zs[32][64];
    __shared__ float2 tab2[512];

    const int tid = threadIdx.x;
    const int blk = blockIdx.x;            // 8b * 16q * 8dt
    const int b   = blk >> 7;
    const int q   = (blk >> 3) & 15;
    const int d0  = (blk & 7) * 64;

    if (tid < 512) {
        double ang = (double)tid * TWO_PI_OVER_512_D;
        tab2[tid] = make_float2((float)cos(ang), (float)sin(ang));
    }
    #pragma unroll
    for (int i = 0; i < 2; ++i) {
        int idx = tid + i * 1024;
        int a = idx >> 6, dl = idx & 63;
        size_t o = (((size_t)b * 16 + q) * 32 + a) * DDIM + d0 + dl;
        zs[a][dl] = make_float2(zre[o], zim[o]);
    }
    __syncthreads();

    const int dl = tid & 63;
    const int j  = tid >> 6;               // 0..15
    const int k  = q + 16 * j;             // 0..255

    float accre = 0.f, accim = 0.f;
    int idx = 0;
    #pragma unroll 4
    for (int a = 0; a < 32; ++a) {
        float2 w = tab2[idx];              // wave-uniform broadcast
        float2 z = zs[a][dl];
        accre = fmaf(z.x,  w.x, accre);
        accre = fmaf(z.y,  w.y, accre);
        accim = fmaf(z.y,  w.x, accim);
        accim = fmaf(-z.x, w.y, accim);
        idx = (idx + k) & 511;
    }

    size_t o = ((size_t)b * DDIM + d0 + dl) * NFREQ + k;
    xre[o] = accre;
    xim[o] = accim;
}

// ---------------------------------------------------------------------------
// Top-32 of |X_m|^2 over m=1..255, per (b,d) column. One wave per column.
// Reads are m-contiguous (coalesced).
// ---------------------------------------------------------------------------
__global__ __launch_bounds__(64) void topk_kernel(const float* __restrict__ xre,
                                                  const float* __restrict__ xim,
                                                  int*   __restrict__ tm,
                                                  float* __restrict__ tre,
                                                  float* __restrict__ tim) {
    const int bd = blockIdx.x;
    const int b  = bd >> 9;
    const int d  = bd & 511;
    const int l  = threadIdx.x;

    const float* pr = xre + ((size_t)b * DDIM + d) * NFREQ;
    const float* pi = xim + ((size_t)b * DDIM + d) * NFREQ;

    float v[4], rs[4], qs[4];
    int   mv[4];
    #pragma unroll
    for (int s = 0; s < 4; ++s) {
        int m = 1 + l + 64 * s;
        if (m <= 255) {
            float r = pr[m], q = pi[m];
            v[s]  = fmaf(r, r, q * q);
            mv[s] = m;
            rs[s] = r;
            qs[s] = q;
        } else {
            v[s] = -1.0f; mv[s] = 0; rs[s] = 0.f; qs[s] = 0.f;
        }
    }

    for (int jj = 0; jj < KSEL; ++jj) {
        float bv = v[0], br = rs[0], bq = qs[0];
        int   bm = mv[0], bs = 0;
        #pragma unroll
        for (int s = 1; s < 4; ++s)
            if (v[s] > bv) { bv = v[s]; br = rs[s]; bq = qs[s]; bm = mv[s]; bs = s; }

        float rv = bv;
        #pragma unroll
        for (int off = 1; off < 64; off <<= 1) {
            float ov = __shfl_xor(rv, off);
            rv = ov > rv ? ov : rv;
        }

        unsigned long long mask = __ballot(bv == rv);
        int owner = __ffsll(mask) - 1;
        bool own = (l == owner);
        if (own) {
            size_t dst = ((size_t)b * KSEL + jj) * DDIM + d;
            tm[dst]  = bm;
            tre[dst] = br;
            tim[dst] = bq;
        }
        v[0] = (own && bs == 0) ? -1.0f : v[0];
        v[1] = (own && bs == 1) ? -1.0f : v[1];
        v[2] = (own && bs == 2) ? -1.0f : v[2];
        v[3] = (own && bs == 3) ? -1.0f : v[3];
    }
}

// ---------------------------------------------------------------------------
// Synthesis via in-register complex rotation (exact table init per j).
// out[b,t,d] = sum_j Re[(a+ig) e^{i 2pi m t/512}],  a=2*Re/512, g=2*Im/512.
// Block: 256 d threads, t-tile 8.  Grid 8b * 2dh * 76tt = 1216 blocks.
// ---------------------------------------------------------------------------
__global__ __launch_bounds__(256) void synth_kernel(const int*   __restrict__ tm,
                                                    const float* __restrict__ tre,
                                                    const float* __restrict__ tim,
                                                    float* __restrict__ out) {
    __shared__ float2 tab2[512];
    const int tid = threadIdx.x;
    for (int i = tid; i < 512; i += 256) {
        double ang = (double)i * TWO_PI_OVER_512_D;
        tab2[i] = make_float2((float)cos(ang), (float)sin(ang));
    }
    __syncthreads();

    const int blk = blockIdx.x;            // 8b * 2dh * 76tt
    const int b   = blk / 152;
    const int r   = blk % 152;
    const int dh  = r / 76;
    const int tt  = r % 76;
    const int d   = dh * 256 + tid;
    const int t0  = tt * 8;

    float acc[8] = {};
    const float sc = 2.0f / 512.0f;

    for (int jp = 0; jp < KSEL; jp += 2) {
        size_t o1 = ((size_t)b * KSEL + jp) * DDIM + d;
        size_t o2 = o1 + DDIM;
        int   m1 = tm[o1],        m2 = tm[o2];
        float a1 = tre[o1] * sc,  a2 = tre[o2] * sc;
        float g1 = tim[o1] * sc,  g2 = tim[o2] * sc;

        float2 w1 = tab2[(m1 * t0) & 511];
        float2 w2 = tab2[(m2 * t0) & 511];
        float2 e1 = tab2[m1];
        float2 e2 = tab2[m2];

        float z1r = a1 * w1.x - g1 * w1.y, z1i = a1 * w1.y + g1 * w1.x;
        float z2r = a2 * w2.x - g2 * w2.y, z2i = a2 * w2.y + g2 * w2.x;

        #pragma unroll
        for (int t = 0; t < 8; ++t) {
            acc[t] += z1r + z2r;
            float n1 = z1r * e1.x - z1i * e1.y;
            z1i      = z1r * e1.y + z1i * e1.x;
            z1r      = n1;
            float n2 = z2r * e2.x - z2i * e2.y;
            z2i      = z2r * e2.y + z2i * e2.x;
            z2r      = n2;
        }
    }

    float* ob = out + (size_t)b * TOUT * DDIM;
    #pragma unroll
    for (int t = 0; t < 8; ++t)
        ob[(size_t)(t0 + t) * DDIM + d] = acc[t];
}

extern "C" void kernel_launch(void* const* d_in, const int* in_sizes, int n_in,
                              void* d_out, int out_size, void* d_ws, size_t ws_size,
                              hipStream_t stream) {
    const float* x   = (const float*)d_in[0];
    float*       out = (float*)d_out;
    float*       ws  = (float*)d_ws;

    float* zre = ws + ZRE_OFF;
    float* zim = ws + ZIM_OFF;
    float* xre = ws + XRE_OFF;
    float* xim = ws + XIM_OFF;
    int*   tm  = (int*)(ws + TM_OFF);
    float* tre = ws + TRE_OFF;
    float* tim = ws + TIM_OFF;

    fft_stage_a<<<512, 256, 0, stream>>>(x, zre, zim);
    fft_stage_b<<<BATCH * 16 * 8, 1024, 0, stream>>>(zre, zim, xre, xim);
    topk_kernel<<<BATCH * DDIM, 64, 0, stream>>>(xre, xim, tm, tre, tim);
    synth_kernel<<<BATCH * 2 * 76, 256, 0, stream>>>(tm, tre, tim, out);
}

// Round 4
// 49.164 us; speedup vs baseline: 4.7309x; 1.2853x over previous
//
#include <hip/hip_runtime.h>
#include <math.h>

#define BATCH 8
#define TLEN  512
#define DDIM  512
#define TOUT  608   // 512 + 96
#define KSEL  32
#define NFREQ 256

#define TWO_PI_OVER_512 0.0122718463030851562f

// ws layout:
//   Xc : [8][512 d][256 m] float2   -> 2,097,152 floats (8 MB)
//   sel: [8][32 j][512 d]  float4 (m_bits, re, im, 0) -> 524,288 floats (2 MB)
#define XC_OFF  0
#define SEL_OFF 2097152

// 16-point DFT twiddles (exact constants), e^{-2pi i n/16} = CC[n] - i*SS[n]
__device__ __constant__ const float CC16[16] = {
     1.f,  0.92387953251128674f,  0.70710678118654752f,  0.38268343236508977f,
     0.f, -0.38268343236508977f, -0.70710678118654752f, -0.92387953251128674f,
    -1.f, -0.92387953251128674f, -0.70710678118654752f, -0.38268343236508977f,
     0.f,  0.38268343236508977f,  0.70710678118654752f,  0.92387953251128674f };
__device__ __constant__ const float SS16[16] = {
     0.f,  0.38268343236508977f,  0.70710678118654752f,  0.92387953251128674f,
     1.f,  0.92387953251128674f,  0.70710678118654752f,  0.38268343236508977f,
     0.f, -0.38268343236508977f, -0.70710678118654752f, -0.92387953251128674f,
    -1.f, -0.92387953251128674f, -0.70710678118654752f, -0.38268343236508977f };

// ---------------------------------------------------------------------------
// Fused FFT: x[b,t,d] -> Xc[b,d,k], k = 0..255, via 512 = 32a x 16c split.
//   Y[q,a] = sum_c x[a+32c] e^{-2pi i c q/16}          (stage A, exact consts)
//   X[k]   = sum_a Y[k&15,a] P_kk(a) w16^{(a*u)&15},   k = kk+32u
//            P_kk(a) = e^{-2pi i a kk/512} (rotating phasor, table-exact init)
// Block: 512 threads, one (b, 16-d tile). Grid 256.
// ---------------------------------------------------------------------------
__global__ __launch_bounds__(512) void fft_fused(const float* __restrict__ x,
                                                 float2* __restrict__ Xc) {
    __shared__ float  xs[512][16];        // 32 KB
    __shared__ float2 ys[8][32][16];      // 32 KB (q-half of Y)
    __shared__ float2 tabn[512];          // (cos, sin)(+2pi n/512), 4 KB

    const int tid = threadIdx.x;
    const int bid = blockIdx.x;
    const int b   = bid >> 5;
    const int d0  = (bid & 31) << 4;

    {   // table init (one entry per thread)
        float s, c;
        sincosf((float)tid * TWO_PI_OVER_512, &s, &c);
        tabn[tid] = make_float2(c, s);
    }

    // load x tile
    const float* xb = x + (size_t)b * TLEN * DDIM + d0;
    #pragma unroll
    for (int i = 0; i < 16; ++i) {
        int idx = tid + i * 512;
        int t = idx >> 4, dd = idx & 15;
        xs[t][dd] = xb[(size_t)t * DDIM + dd];
    }
    __syncthreads();

    // ---- stage A: radix-16, thread = (a, d) ----
    const int aA = tid >> 4;     // 0..31
    const int dA = tid & 15;
    float xv[16];
    #pragma unroll
    for (int c = 0; c < 16; ++c) xv[c] = xs[aA + 32 * c][dA];

    float yr[16], yi[16];
    #pragma unroll
    for (int q = 0; q < 16; ++q) {
        float sr = 0.f, si = 0.f;
        #pragma unroll
        for (int c = 0; c < 16; ++c) {
            const int n = (c * q) & 15;
            sr = fmaf(xv[c],  CC16[n], sr);
            si = fmaf(xv[c], -SS16[n], si);
        }
        yr[q] = sr; yi[q] = si;
    }

    // ---- stage B thread mapping ----
    const int ahalf = tid & 1;           // a-half: 0 -> a<16, 1 -> a>=16
    const int dB    = (tid >> 1) & 15;
    const int kki   = tid >> 5;          // 0..15

    float2* Xrow;
    #pragma unroll
    for (int h = 0; h < 2; ++h) {
        // publish Y half: q in [8h, 8h+8)
        #pragma unroll
        for (int q = 0; q < 8; ++q)
            ys[q][aA][dA] = make_float2(yr[q + 8 * h], yi[q + 8 * h]);
        __syncthreads();

        const int kk = kki + (kki & 8) + 8 * h;   // h=0: {0..7,16..23}; h=1: {8..15,24..31}
        const int qq = (kk & 15) & 7;             // row within ys

        float Pr, Pi;
        if (ahalf == 0) { Pr = 1.f; Pi = 0.f; }
        else { float2 w = tabn[(16 * kk) & 511]; Pr = w.x; Pi = -w.y; }
        const float2 st = tabn[kk];               // step e^{-2pi i kk/512} = (st.x, -st.y)

        float ar[8] = {}, ai[8] = {};
        #pragma unroll
        for (int aa = 0; aa < 16; ++aa) {
            const int arow = ahalf * 16 + aa;     // (arow*u)&15 == (aa*u)&15
            float2 Y = ys[qq][arow][dB];
            float zr = Y.x * Pr - Y.y * Pi;
            float zi = Y.x * Pi + Y.y * Pr;
            #pragma unroll
            for (int u = 0; u < 8; ++u) {
                const int n = (aa * u) & 15;
                ar[u] = fmaf(zr, CC16[n], fmaf(zi,  SS16[n], ar[u]));
                ai[u] = fmaf(zi, CC16[n], fmaf(-zr, SS16[n], ai[u]));
            }
            float npr = fmaf(Pr, st.x,  Pi * st.y);
            Pi        = fmaf(Pi, st.x, -Pr * st.y);
            Pr        = npr;
        }

        // combine a-halves (partner = lane^1), split stores by u
        #pragma unroll
        for (int u = 0; u < 8; ++u) {
            ar[u] += __shfl_xor(ar[u], 1);
            ai[u] += __shfl_xor(ai[u], 1);
        }
        Xrow = Xc + ((size_t)b * DDIM + d0 + dB) * NFREQ;
        #pragma unroll
        for (int v = 0; v < 4; ++v) {
            const int u = ahalf * 4 + v;
            Xrow[kk + 32 * u] = make_float2(ar[u], ai[u]);
        }
        __syncthreads();   // before overwriting ys with next half
    }
}

// ---------------------------------------------------------------------------
// Top-32 of |X_m|^2 over m=1..255 per (b,d) column. One wave per column.
// Writes sel[b][j][d] = (m_bits, re, im, 0).
// ---------------------------------------------------------------------------
__global__ __launch_bounds__(64) void topk_kernel(const float2* __restrict__ Xc,
                                                  float4* __restrict__ sel) {
    const int bd = blockIdx.x;
    const int b  = bd >> 9;
    const int d  = bd & 511;
    const int l  = threadIdx.x;

    const float2* col = Xc + ((size_t)b * DDIM + d) * NFREQ;

    float v[4], rs[4], qs[4];
    int   mv[4];
    #pragma unroll
    for (int s = 0; s < 4; ++s) {
        int m = 1 + l + 64 * s;
        if (m <= 255) {
            float2 z = col[m];
            v[s]  = fmaf(z.x, z.x, z.y * z.y);
            mv[s] = m; rs[s] = z.x; qs[s] = z.y;
        } else {
            v[s] = -1.0f; mv[s] = 0; rs[s] = 0.f; qs[s] = 0.f;
        }
    }

    for (int jj = 0; jj < KSEL; ++jj) {
        float bv = v[0], br = rs[0], bq = qs[0];
        int   bm = mv[0], bs = 0;
        #pragma unroll
        for (int s = 1; s < 4; ++s)
            if (v[s] > bv) { bv = v[s]; br = rs[s]; bq = qs[s]; bm = mv[s]; bs = s; }

        float rv = bv;
        #pragma unroll
        for (int off = 1; off < 64; off <<= 1) {
            float ov = __shfl_xor(rv, off);
            rv = ov > rv ? ov : rv;
        }

        unsigned long long mask = __ballot(bv == rv);
        int owner = __ffsll(mask) - 1;
        bool own = (l == owner);
        if (own) {
            sel[((size_t)b * KSEL + jj) * DDIM + d] =
                make_float4(__int_as_float(bm), br, bq, 0.f);
        }
        v[0] = (own && bs == 0) ? -1.0f : v[0];
        v[1] = (own && bs == 1) ? -1.0f : v[1];
        v[2] = (own && bs == 2) ? -1.0f : v[2];
        v[3] = (own && bs == 3) ? -1.0f : v[3];
    }
}

// ---------------------------------------------------------------------------
// Synthesis via in-register complex rotation.  t-tile 19 -> grid exactly 512.
// out[b,t,d] = sum_j 2/512 * Re[(re + i*im) e^{i 2pi m t/512}]
// ---------------------------------------------------------------------------
__global__ __launch_bounds__(256) void synth_kernel(const float4* __restrict__ sel,
                                                    float* __restrict__ out) {
    __shared__ float2 tab2[512];
    const int tid = threadIdx.x;
    #pragma unroll
    for (int i = 0; i < 2; ++i) {
        int n = tid + i * 256;
        float s, c;
        sincosf((float)n * TWO_PI_OVER_512, &s, &c);
        tab2[n] = make_float2(c, s);
    }
    __syncthreads();

    const int blk = blockIdx.x;        // 8b * 2dh * 32tt
    const int b   = blk >> 6;
    const int dh  = (blk >> 5) & 1;
    const int tt  = blk & 31;
    const int d   = dh * 256 + tid;
    const int t0  = tt * 19;

    float acc[19] = {};
    const float sc = 2.0f / 512.0f;

    for (int jp = 0; jp < KSEL; jp += 2) {
        float4 s1 = sel[((size_t)b * KSEL + jp) * DDIM + d];
        float4 s2 = sel[((size_t)b * KSEL + jp + 1) * DDIM + d];
        int   m1 = __float_as_int(s1.x), m2 = __float_as_int(s2.x);
        float a1 = s1.y * sc, g1 = s1.z * sc;
        float a2 = s2.y * sc, g2 = s2.z * sc;

        float2 w1 = tab2[(m1 * t0) & 511];
        float2 w2 = tab2[(m2 * t0) & 511];
        float2 e1 = tab2[m1];
        float2 e2 = tab2[m2];

        float z1r = a1 * w1.x - g1 * w1.y, z1i = a1 * w1.y + g1 * w1.x;
        float z2r = a2 * w2.x - g2 * w2.y, z2i = a2 * w2.y + g2 * w2.x;

        #pragma unroll
        for (int t = 0; t < 19; ++t) {
            acc[t] += z1r + z2r;
            float n1 = z1r * e1.x - z1i * e1.y;
            z1i      = z1r * e1.y + z1i * e1.x;
            z1r      = n1;
            float n2 = z2r * e2.x - z2i * e2.y;
            z2i      = z2r * e2.y + z2i * e2.x;
            z2r      = n2;
        }
    }

    float* ob = out + (size_t)b * TOUT * DDIM;
    #pragma unroll
    for (int t = 0; t < 19; ++t)
        ob[(size_t)(t0 + t) * DDIM + d] = acc[t];
}

extern "C" void kernel_launch(void* const* d_in, const int* in_sizes, int n_in,
                              void* d_out, int out_size, void* d_ws, size_t ws_size,
                              hipStream_t stream) {
    const float* x   = (const float*)d_in[0];
    float*       out = (float*)d_out;
    float*       ws  = (float*)d_ws;

    float2* Xc  = (float2*)(ws + XC_OFF);
    float4* sel = (float4*)(ws + SEL_OFF);

    fft_fused<<<256, 512, 0, stream>>>(x, Xc);
    topk_kernel<<<BATCH * DDIM, 64, 0, stream>>>(Xc, sel);
    synth_kernel<<<512, 256, 0, stream>>>(sel, out);
}

// Round 5
// 38.182 us; speedup vs baseline: 6.0918x; 1.2876x over previous
//
#include <hip/hip_runtime.h>
#include <math.h>

#define BATCH 8
#define TLEN  512
#define DDIM  512
#define TOUT  608   // 512 + 96
#define KSEL  32
#define NFREQ 256
#define DT    8     // d columns per block

#define TWO_PI_OVER_512 0.0122718463030851562f

// 16-point DFT twiddles (exact constants), e^{-2pi i n/16} = CC[n] - i*SS[n]
__device__ __constant__ const float CC16[16] = {
     1.f,  0.92387953251128674f,  0.70710678118654752f,  0.38268343236508977f,
     0.f, -0.38268343236508977f, -0.70710678118654752f, -0.92387953251128674f,
    -1.f, -0.92387953251128674f, -0.70710678118654752f, -0.38268343236508977f,
     0.f,  0.38268343236508977f,  0.70710678118654752f,  0.92387953251128674f };
__device__ __constant__ const float SS16[16] = {
     0.f,  0.38268343236508977f,  0.70710678118654752f,  0.92387953251128674f,
     1.f,  0.92387953251128674f,  0.70710678118654752f,  0.38268343236508977f,
     0.f, -0.38268343236508977f, -0.70710678118654752f, -0.92387953251128674f,
    -1.f, -0.92387953251128674f, -0.70710678118654752f, -0.38268343236508977f };

// ---------------------------------------------------------------------------
// One block = (b, 8-d tile). Phases:
//   A: radix-16 DFT  (t = a + 32c), thread = (a, d)
//   B: 32-point combine with rotating phasor, full 256-m spectrum -> LDS
//   topk: per-column top-32 via binary search on |X|^2 bit patterns
//   synth: 608-t extrapolation, 4-way ILP rotation chains
// Grid 512 x 256 threads.
// ---------------------------------------------------------------------------
__global__ __launch_bounds__(256, 2) void fourier_fused(const float* __restrict__ x,
                                                        float* __restrict__ out) {
    __shared__ float  ysr[8][33][9];     // [q][arow(+pad)][d(+pad)]
    __shared__ float  ysi[8][33][9];
    __shared__ float2 Xl[DT][259];       // [d][m], stride 259 vs bank conflicts
    __shared__ float4 selL[DT][KSEL];    // (m_bits, re, im, 0)
    __shared__ float2 tab2[512];         // (cos,sin)(+2pi n/512)

    const int tid = threadIdx.x;
    const int bid = blockIdx.x;          // 8b x 64 d-tiles
    const int b   = bid >> 6;
    const int d0  = (bid & 63) * DT;

    // twiddle table (hardware sincos path)
    #pragma unroll
    for (int i = 0; i < 2; ++i) {
        int n = tid + i * 256;
        float s, c;
        sincosf((float)n * TWO_PI_OVER_512, &s, &c);
        tab2[n] = make_float2(c, s);
    }

    // ---- stage A: thread = (aA, dA), 16-point DFT over c ----
    const int aA = tid >> 3;             // 0..31
    const int dA = tid & 7;
    const float* xb = x + ((size_t)b * TLEN + aA) * DDIM + d0 + dA;
    float xv[16];
    #pragma unroll
    for (int c = 0; c < 16; ++c)
        xv[c] = xb[(size_t)c * 32 * DDIM];

    float yr[16], yi[16];
    #pragma unroll
    for (int q = 0; q < 16; ++q) {
        float sr = 0.f, si = 0.f;
        #pragma unroll
        for (int c = 0; c < 16; ++c) {
            const int n = (c * q) & 15;
            sr = fmaf(xv[c],  CC16[n], sr);
            si = fmaf(xv[c], -SS16[n], si);
        }
        yr[q] = sr; yi[q] = si;
    }

    // ---- stage B: thread = (ahalf, dB, kki) ----
    const int ahalf = tid & 1;
    const int dB    = (tid >> 1) & 7;
    const int kki   = tid >> 4;          // 0..15

    #pragma unroll
    for (int h = 0; h < 2; ++h) {
        __syncthreads();                 // prior ys reads done (and tab2/x ready)
        #pragma unroll
        for (int q = 0; q < 8; ++q) {
            ysr[q][aA][dA] = yr[q + 8 * h];
            ysi[q][aA][dA] = yi[q + 8 * h];
        }
        __syncthreads();

        const int kk = kki + (kki & 8) + 8 * h;   // kk&15 in [8h, 8h+8)
        const int qq = kk & 7;

        float Pr, Pi;
        if (ahalf == 0) { Pr = 1.f; Pi = 0.f; }
        else {
            float s, c;
            sincosf((float)((16 * kk) & 511) * TWO_PI_OVER_512, &s, &c);
            Pr = c; Pi = -s;
        }
        float sts, stc;
        sincosf((float)kk * TWO_PI_OVER_512, &sts, &stc);  // step e^{-2pi i kk/512}

        float ar[8] = {}, ai[8] = {};
        #pragma unroll
        for (int aa = 0; aa < 16; ++aa) {
            const int arow = ahalf * 16 + aa;
            float Yr = ysr[qq][arow][dB];
            float Yi = ysi[qq][arow][dB];
            float zr = Yr * Pr - Yi * Pi;
            float zi = Yr * Pi + Yi * Pr;
            #pragma unroll
            for (int u = 0; u < 8; ++u) {
                const int n = (aa * u) & 15;
                ar[u] = fmaf(zr, CC16[n], fmaf(zi,  SS16[n], ar[u]));
                ai[u] = fmaf(zi, CC16[n], fmaf(-zr, SS16[n], ai[u]));
            }
            float npr = fmaf(Pr, stc,  Pi * sts);
            Pi        = fmaf(Pi, stc, -Pr * sts);
            Pr        = npr;
        }

        // combine a-halves (partner lane = tid^1 flips ahalf)
        #pragma unroll
        for (int u = 0; u < 8; ++u) {
            ar[u] += __shfl_xor(ar[u], 1);
            ai[u] += __shfl_xor(ai[u], 1);
        }
        #pragma unroll
        for (int v = 0; v < 4; ++v) {
            const int u = ahalf * 4 + v;
            Xl[dB][kk + 32 * u] = make_float2(ar[u], ai[u]);
        }
    }
    __syncthreads();   // Xl complete

    // ---- topk: wave w handles columns 2w, 2w+1 ----
    {
        const int l = tid & 63;
        const int w = tid >> 6;          // 0..3
        const unsigned long long below = ((unsigned long long)1 << l) - 1;

        for (int cc = 0; cc < 2; ++cc) {
            const int dd = w * 2 + cc;
            float zr[4], zi[4];
            unsigned vb[4];
            int mm[4];
            #pragma unroll
            for (int s = 0; s < 4; ++s) {
                int m = 1 + l + 64 * s;
                mm[s] = m;
                if (m <= 255) {
                    float2 z = Xl[dd][m];
                    zr[s] = z.x; zi[s] = z.y;
                    vb[s] = __float_as_uint(fmaf(z.x, z.x, z.y * z.y));
                } else { zr[s] = 0.f; zi[s] = 0.f; vb[s] = 0u; }
            }

            unsigned tau = 0;
            for (int bit = 30; bit >= 0; --bit) {
                unsigned cand = tau | (1u << bit);
                int cnt = __popcll(__ballot(vb[0] >= cand))
                        + __popcll(__ballot(vb[1] >= cand))
                        + __popcll(__ballot(vb[2] >= cand))
                        + __popcll(__ballot(vb[3] >= cand));
                if (cnt >= KSEL) tau = cand;
            }

            unsigned long long bgt[4], beq[4];
            int cgt = 0;
            #pragma unroll
            for (int s = 0; s < 4; ++s) {
                bgt[s] = __ballot(vb[s] > tau);
                beq[s] = __ballot(vb[s] == tau);
                cgt += __popcll(bgt[s]);
            }
            const int need = KSEL - cgt;   // ties to take at == tau

            int bg = 0, be = 0;
            #pragma unroll
            for (int s = 0; s < 4; ++s) {
                if (vb[s] > tau) {
                    int slot = bg + __popcll(bgt[s] & below);
                    selL[dd][slot] = make_float4(__int_as_float(mm[s]), zr[s], zi[s], 0.f);
                } else if (vb[s] == tau) {
                    int r = be + __popcll(beq[s] & below);
                    if (r < need)
                        selL[dd][cgt + r] = make_float4(__int_as_float(mm[s]), zr[s], zi[s], 0.f);
                }
                bg += __popcll(bgt[s]);
                be += __popcll(beq[s]);
            }
        }
    }
    __syncthreads();   // selL complete

    // ---- synth: thread = (dd, 19-t chunk), 4-way j ILP ----
    {
        const int dd = tid & 7;
        const int tc = tid >> 3;         // 0..31
        const int t0 = tc * 19;
        const float sc = 2.0f / 512.0f;

        float acc[19] = {};

        #pragma unroll 2
        for (int g = 0; g < 8; ++g) {
            float zr_[4], zi_[4], ex_[4], ey_[4];
            #pragma unroll
            for (int i = 0; i < 4; ++i) {
                float4 sv = selL[dd][g * 4 + i];
                int   m  = __float_as_int(sv.x);
                float a  = sv.y * sc;
                float gg = sv.z * sc;
                float2 wv = tab2[(m * t0) & 511];
                float2 ev = tab2[m];
                zr_[i] = a * wv.x - gg * wv.y;
                zi_[i] = a * wv.y + gg * wv.x;
                ex_[i] = ev.x; ey_[i] = ev.y;
            }
            #pragma unroll
            for (int t = 0; t < 19; ++t) {
                acc[t] += (zr_[0] + zr_[1]) + (zr_[2] + zr_[3]);
                #pragma unroll
                for (int i = 0; i < 4; ++i) {
                    float nr = zr_[i] * ex_[i] - zi_[i] * ey_[i];
                    zi_[i]   = zr_[i] * ey_[i] + zi_[i] * ex_[i];
                    zr_[i]   = nr;
                }
            }
        }

        float* ob = out + (size_t)b * TOUT * DDIM + d0 + dd;
        #pragma unroll
        for (int t = 0; t < 19; ++t)
            ob[(size_t)(t0 + t) * DDIM] = acc[t];
    }
}

extern "C" void kernel_launch(void* const* d_in, const int* in_sizes, int n_in,
                              void* d_out, int out_size, void* d_ws, size_t ws_size,
                              hipStream_t stream) {
    const float* x   = (const float*)d_in[0];
    float*       out = (float*)d_out;
    fourier_fused<<<BATCH * 64, 256, 0, stream>>>(x, out);
}

// Round 6
// 35.558 us; speedup vs baseline: 6.5412x; 1.0738x over previous
//
#include <hip/hip_runtime.h>
#include <math.h>

#define BATCH 8
#define TLEN  512
#define DDIM  512
#define TOUT  608   // 512 + 96
#define KSEL  32
#define DT    8     // d columns per block

#define TWO_PI_OVER_512 0.0122718463030851562f

// 16-point DFT twiddles (exact constants), e^{-2pi i n/16} = CC[n] - i*SS[n]
__device__ __constant__ const float CC16[16] = {
     1.f,  0.92387953251128674f,  0.70710678118654752f,  0.38268343236508977f,
     0.f, -0.38268343236508977f, -0.70710678118654752f, -0.92387953251128674f,
    -1.f, -0.92387953251128674f, -0.70710678118654752f, -0.38268343236508977f,
     0.f,  0.38268343236508977f,  0.70710678118654752f,  0.92387953251128674f };
__device__ __constant__ const float SS16[16] = {
     0.f,  0.38268343236508977f,  0.70710678118654752f,  0.92387953251128674f,
     1.f,  0.92387953251128674f,  0.70710678118654752f,  0.38268343236508977f,
     0.f, -0.38268343236508977f, -0.70710678118654752f, -0.92387953251128674f,
    -1.f, -0.92387953251128674f, -0.70710678118654752f, -0.38268343236508977f };

// ---------------------------------------------------------------------------
// One block = (b, 8-d tile). Phases:
//   A: radix-16 DFT (t = a + 32c); per-h-half q rows computed in-loop (VGPR)
//   B: 32-point combine with rotating phasor -> full 256-m spectrum in LDS
//   topk: binary search on |X|^2 bit patterns + ballot compaction; tab2 init
//   synth: t in [0,512) with 4-way ILP rotation chains; rows 0..95 duplicated
//          to 512..607 (the synthesized signal is exactly 512-periodic)
// LDS ~35.5 KB, target 4 blocks/CU.
// ---------------------------------------------------------------------------
__global__ __launch_bounds__(256, 4) void fourier_fused(const float* __restrict__ x,
                                                        float* __restrict__ out) {
    __shared__ float2 Xl[DT][257];                       // 16,448 B
    __shared__ __align__(16) unsigned char uni[19008];   // ys | (selL + tab2)
    float*  ysr  = (float*)uni;                          // [8][33][9]
    float*  ysi  = ysr + 8 * 33 * 9;
    float4* selL = (float4*)uni;                         // [8][stride 33]
    float2* tab2 = (float2*)(uni + 8 * 33 * 16);         // [512], offset 4224

    const int tid = threadIdx.x;
    const int bid = blockIdx.x;          // 8b x 64 d-tiles
    const int b   = bid >> 6;
    const int d0  = (bid & 63) * DT;

    // ---- stage A input: thread = (aA, dA) ----
    const int aA = tid >> 3;             // 0..31
    const int dA = tid & 7;
    const float* xb = x + ((size_t)b * TLEN + aA) * DDIM + d0 + dA;
    float xv[16];
    #pragma unroll
    for (int c = 0; c < 16; ++c)
        xv[c] = xb[(size_t)c * 32 * DDIM];

    // ---- stage B mapping ----
    const int ahalf = tid & 1;
    const int dB    = (tid >> 1) & 7;
    const int kki   = tid >> 4;          // 0..15

    #pragma unroll
    for (int h = 0; h < 2; ++h) {
        __syncthreads();                 // ys readers from previous half done
        // compute q rows [8h, 8h+8) from xv and publish
        #pragma unroll
        for (int qn = 0; qn < 8; ++qn) {
            const int q = qn + 8 * h;
            float sr = 0.f, si = 0.f;
            #pragma unroll
            for (int c = 0; c < 16; ++c) {
                const int n = (c * q) & 15;
                sr = fmaf(xv[c],  CC16[n], sr);
                si = fmaf(xv[c], -SS16[n], si);
            }
            ysr[(qn * 33 + aA) * 9 + dA] = sr;
            ysi[(qn * 33 + aA) * 9 + dA] = si;
        }
        __syncthreads();

        const int kk = kki + (kki & 8) + 8 * h;   // h=0:{0..7,16..23} h=1:{8..15,24..31}
        const int qq = kk & 7;

        float Pr, Pi;
        if (ahalf == 0) { Pr = 1.f; Pi = 0.f; }
        else {
            float s, c;
            sincosf((float)((16 * kk) & 511) * TWO_PI_OVER_512, &s, &c);
            Pr = c; Pi = -s;
        }
        float sts, stc;
        sincosf((float)kk * TWO_PI_OVER_512, &sts, &stc);  // e^{-2pi i kk/512}

        float ar[8] = {}, ai[8] = {};
        #pragma unroll
        for (int aa = 0; aa < 16; ++aa) {
            const int arow = ahalf * 16 + aa;     // (arow*u)&15 == (aa*u)&15
            float Yr = ysr[(qq * 33 + arow) * 9 + dB];
            float Yi = ysi[(qq * 33 + arow) * 9 + dB];
            float zr = Yr * Pr - Yi * Pi;
            float zi = Yr * Pi + Yi * Pr;
            #pragma unroll
            for (int u = 0; u < 8; ++u) {
                const int n = (aa * u) & 15;
                ar[u] = fmaf(zr, CC16[n], fmaf(zi,  SS16[n], ar[u]));
                ai[u] = fmaf(zi, CC16[n], fmaf(-zr, SS16[n], ai[u]));
            }
            float npr = fmaf(Pr, stc,  Pi * sts);
            Pi        = fmaf(Pi, stc, -Pr * sts);
            Pr        = npr;
        }

        // combine a-halves (partner lane = tid^1 flips ahalf)
        #pragma unroll
        for (int u = 0; u < 8; ++u) {
            ar[u] += __shfl_xor(ar[u], 1);
            ai[u] += __shfl_xor(ai[u], 1);
        }
        #pragma unroll
        for (int v = 0; v < 4; ++v) {
            const int u = ahalf * 4 + v;
            Xl[dB][kk + 32 * u] = make_float2(ar[u], ai[u]);
        }
    }
    __syncthreads();   // Xl complete; ys dead from here (union reuse OK)

    // ---- topk (+ tab2 init into the union) ----
    {
        #pragma unroll
        for (int i = 0; i < 2; ++i) {
            int n = tid + i * 256;
            float s, c;
            sincosf((float)n * TWO_PI_OVER_512, &s, &c);
            tab2[n] = make_float2(c, s);
        }

        const int l = tid & 63;
        const int w = tid >> 6;          // 0..3
        const unsigned long long below = ((unsigned long long)1 << l) - 1;

        for (int cc = 0; cc < 2; ++cc) {
            const int dd = w * 2 + cc;
            float zr[4], zi[4];
            unsigned vb[4];
            int mm[4];
            #pragma unroll
            for (int s = 0; s < 4; ++s) {
                int m = 1 + l + 64 * s;
                mm[s] = m;
                if (m <= 255) {
                    float2 z = Xl[dd][m];
                    zr[s] = z.x; zi[s] = z.y;
                    vb[s] = __float_as_uint(fmaf(z.x, z.x, z.y * z.y));
                } else { zr[s] = 0.f; zi[s] = 0.f; vb[s] = 0u; }
            }

            unsigned tau = 0;
            for (int bit = 30; bit >= 0; --bit) {
                unsigned cand = tau | (1u << bit);
                int cnt = __popcll(__ballot(vb[0] >= cand))
                        + __popcll(__ballot(vb[1] >= cand))
                        + __popcll(__ballot(vb[2] >= cand))
                        + __popcll(__ballot(vb[3] >= cand));
                if (cnt >= KSEL) tau = cand;
            }

            unsigned long long bgt[4], beq[4];
            int cgt = 0;
            #pragma unroll
            for (int s = 0; s < 4; ++s) {
                bgt[s] = __ballot(vb[s] > tau);
                beq[s] = __ballot(vb[s] == tau);
                cgt += __popcll(bgt[s]);
            }
            const int need = KSEL - cgt;   // ties taken at == tau

            int bg = 0, be = 0;
            #pragma unroll
            for (int s = 0; s < 4; ++s) {
                if (vb[s] > tau) {
                    int slot = bg + __popcll(bgt[s] & below);
                    selL[dd * 33 + slot] = make_float4(__int_as_float(mm[s]), zr[s], zi[s], 0.f);
                } else if (vb[s] == tau) {
                    int r = be + __popcll(beq[s] & below);
                    if (r < need)
                        selL[dd * 33 + cgt + r] = make_float4(__int_as_float(mm[s]), zr[s], zi[s], 0.f);
                }
                bg += __popcll(bgt[s]);
                be += __popcll(beq[s]);
            }
        }
    }
    __syncthreads();   // selL + tab2 ready

    // ---- synth: thread = (dd, 16-t chunk); rows 0..95 also stored at +512 ----
    {
        const int dd = tid & 7;
        const int tc = tid >> 3;         // 0..31
        const int t0 = tc * 16;
        const float sc = 2.0f / 512.0f;

        float acc[16] = {};

        #pragma unroll 2
        for (int g = 0; g < 8; ++g) {
            float zr_[4], zi_[4], ex_[4], ey_[4];
            #pragma unroll
            for (int i = 0; i < 4; ++i) {
                float4 sv = selL[dd * 33 + g * 4 + i];
                int   m  = __float_as_int(sv.x);
                float a  = sv.y * sc;
                float gg = sv.z * sc;
                float2 wv = tab2[(m * t0) & 511];
                float2 ev = tab2[m];
                zr_[i] = a * wv.x - gg * wv.y;
                zi_[i] = a * wv.y + gg * wv.x;
                ex_[i] = ev.x; ey_[i] = ev.y;
            }
            #pragma unroll
            for (int t = 0; t < 16; ++t) {
                acc[t] += (zr_[0] + zr_[1]) + (zr_[2] + zr_[3]);
                #pragma unroll
                for (int i = 0; i < 4; ++i) {
                    float nr = zr_[i] * ex_[i] - zi_[i] * ey_[i];
                    zi_[i]   = zr_[i] * ey_[i] + zi_[i] * ex_[i];
                    zr_[i]   = nr;
                }
            }
        }

        float* ob = out + (size_t)b * TOUT * DDIM + d0 + dd;
        if (t0 < 96) {
            #pragma unroll
            for (int t = 0; t < 16; ++t) {
                ob[(size_t)(t0 + t) * DDIM]       = acc[t];
                ob[(size_t)(t0 + t + 512) * DDIM] = acc[t];
            }
        } else {
            #pragma unroll
            for (int t = 0; t < 16; ++t)
                ob[(size_t)(t0 + t) * DDIM] = acc[t];
        }
    }
}

extern "C" void kernel_launch(void* const* d_in, const int* in_sizes, int n_in,
                              void* d_out, int out_size, void* d_ws, size_t ws_size,
                              hipStream_t stream) {
    const float* x   = (const float*)d_in[0];
    float*       out = (float*)d_out;
    fourier_fused<<<BATCH * 64, 256, 0, stream>>>(x, out);
}